// Round 4
// baseline (204.815 us; speedup 1.0000x reference)
//
#include <hip/hip_runtime.h>

// Semantics (verified through R0-R9 of previous session):
//   ABI: tokens (N,D) fp32, coords (N,2) int32, weight (D,1,3,3) fp32,
//   straight taps, straight scatter, zero padding/empty cells, bias added,
//   OUTPUT IS (D, N) flat (np advanced indexing, missing .T).
// R13: identical math to R2 (74 us). Latency-bound -> raise occupancy cap:
//   - LDS halved to 16KB (s_out[16][256]); epilogue runs in two 16-token
//     halves. Both 64B half-lines of each output line come from the SAME
//     block (same CU/XCD L2) ~us apart -> merge before writeback.
//   - cap: 10 blocks/CU, min(40,32,VGPR~32) = 32 waves/CU (was 20).
//   - no explicit pipeline (keep VGPR ~56 so 8 waves/SIMD remain legal).
#define DD 256
#define HH 384
#define WW 384
#define NTOK 65536
#define TPB 32   // tokens per block
#define TPW 8    // tokens per wave
#define HALF 16  // tokens per epilogue half

// ---------------------------------------------------------------------------
// Prep: weight (D,9) -> wT (9,D) (straight, no flip); bias copied.
// ---------------------------------------------------------------------------
__global__ __launch_bounds__(256) void prep_kernel(
    const float* __restrict__ weight, const float* __restrict__ bias,
    float* __restrict__ wT, float* __restrict__ biasf)
{
    int ch = threadIdx.x;  // 0..255
    #pragma unroll
    for (int k = 0; k < 9; ++k)
        wT[k * DD + ch] = weight[ch * 9 + k];
    biasf[ch] = bias[ch];
}

// ---------------------------------------------------------------------------
// Scatter (straight): pos_map[r*W + c] = token index (pre-filled with -1)
// ---------------------------------------------------------------------------
__global__ __launch_bounds__(256) void scatter_pos_kernel(
    const int* __restrict__ coords, int* __restrict__ pos_map)
{
    int n = blockIdx.x * blockDim.x + threadIdx.x;
    if (n < NTOK) {
        int r = coords[2 * n + 0];
        int c = coords[2 * n + 1];
        pos_map[r * WW + c] = n;
    }
}

// ---------------------------------------------------------------------------
// Main: 4 waves/block, 8 tokens per wave, split as 4 in each epilogue half.
// Wave w owns block-relative tokens {w*4..w*4+3} u {16+w*4..16+w*4+3}.
// Phase A: scalar (SMEM) loads of coords + all 72 pos_map entries.
// Per half: gather+FMA (compiler-scheduled), 16KB LDS transpose, 64B store
// per channel; the block's second half completes each 128B line.
// ---------------------------------------------------------------------------
__global__ __launch_bounds__(256) void conv_gather_kernel(
    const float* __restrict__ tokens,
    const int*   __restrict__ coords,
    const float* __restrict__ wT,      // (9, D)
    const float* __restrict__ biasf,   // (D,)
    const int*   __restrict__ pos_map,
    float*       __restrict__ out)     // (D, N) layout!
{
    __shared__ float s_out[HALF][DD];           // 16 KB

    const int wave = threadIdx.x >> 6;          // 0..3
    const int lane = threadIdx.x & 63;
    const int c0   = lane * 4;
    const int nb   = __builtin_amdgcn_readfirstlane(blockIdx.x * TPB);
    const int w4i  = __builtin_amdgcn_readfirstlane(wave * 4);

    const float4 bias4 = *(const float4*)(biasf + c0);
    float4 w4[9];
    #pragma unroll
    for (int k = 0; k < 9; ++k)
        w4[k] = *(const float4*)(wT + k * DD + c0);

    // ---- Phase A: scalar loads. All addresses wave-uniform -> s_load. ----
    // midx holds token row, or (n | sign bit) when the tap is invalid.
    int midx[TPW][9];
    #pragma unroll
    for (int j = 0; j < TPW; ++j) {
        const int brel = (j >> 2) * HALF + w4i + (j & 3);
        const int n    = nb + brel;
        const int r = coords[2 * n + 0];        // uniform -> s_load
        const int c = coords[2 * n + 1];
        #pragma unroll
        for (int dy = 0; dy < 3; ++dy) {
            #pragma unroll
            for (int dx = 0; dx < 3; ++dx) {
                const int k  = dy * 3 + dx;
                const int rr = r + dy - 1;
                const int cc = c + dx - 1;
                const bool in_bounds = (rr >= 0) & (rr < HH) & (cc >= 0) & (cc < WW);
                const int  pidx = in_bounds ? (rr * WW + cc) : 0;
                const int  m    = pos_map[pidx];    // uniform -> s_load
                const bool use  = in_bounds & (m >= 0);
                midx[j][k] = use ? m : (n | 0x80000000);  // self row, sel=0
            }
        }
    }

    // ---- Two halves: compute 16 tokens, transpose, store 64B/channel. ----
    #pragma unroll
    for (int h = 0; h < 2; ++h) {
        #pragma unroll
        for (int j = 0; j < 4; ++j) {
            const int jj = h * 4 + j;
            float4 acc = bias4;
            #pragma unroll
            for (int k = 0; k < 9; ++k) {
                const int   mi  = midx[jj][k];
                const int   row = mi & 0x7fffffff;          // scalar
                const float sel = (mi >= 0) ? 1.0f : 0.0f;  // scalar
                const float4 t = *(const float4*)(tokens + (size_t)row * DD + c0);
                acc.x += w4[k].x * (sel * t.x);
                acc.y += w4[k].y * (sel * t.y);
                acc.z += w4[k].z * (sel * t.z);
                acc.w += w4[k].w * (sel * t.w);
            }
            *(float4*)&s_out[w4i + j][c0] = acc;
        }
        __syncthreads();

        // Thread ch gathers this half's 16 tokens for channel ch and stores
        // 64B contiguous; the block's other half completes the 128B line.
        {
            const int ch = threadIdx.x;
            float* dst = out + (size_t)ch * NTOK + nb + h * HALF;
            float v[HALF];
            #pragma unroll
            for (int t = 0; t < HALF; ++t)
                v[t] = s_out[t][ch];
            #pragma unroll
            for (int q = 0; q < 4; ++q) {
                float4 o;
                o.x = v[4 * q + 0]; o.y = v[4 * q + 1];
                o.z = v[4 * q + 2]; o.w = v[4 * q + 3];
                *(float4*)(dst + 4 * q) = o;
            }
        }
        __syncthreads();   // protect s_out before next half overwrites
    }
}

// ---------------------------------------------------------------------------
extern "C" void kernel_launch(void* const* d_in, const int* in_sizes, int n_in,
                              void* d_out, int out_size, void* d_ws, size_t ws_size,
                              hipStream_t stream)
{
    const float* tokens = (const float*)d_in[0];
    const int*   coords = (const int*)d_in[1];
    const float* weight = (const float*)d_in[2];
    const float* bias   = (const float*)d_in[3];
    float* out = (float*)d_out;

    // Workspace layout:
    //   [0, 9216)       wT: 9*256 fp32
    //   [9216, 10240)   biasf: 256 fp32
    //   [16384, 606208) pos_map: H*W int32
    char* ws = (char*)d_ws;
    float* wT      = (float*)ws;
    float* biasf   = (float*)(ws + 9216);
    int*   pos_map = (int*)(ws + 16384);

    hipMemsetAsync(pos_map, 0xFF, (size_t)HH * WW * sizeof(int), stream);
    prep_kernel<<<1, 256, 0, stream>>>(weight, bias, wT, biasf);
    scatter_pos_kernel<<<(NTOK + 255) / 256, 256, 0, stream>>>(coords, pos_map);
    conv_gather_kernel<<<NTOK / TPB, 256, 0, stream>>>(tokens, coords, wT, biasf,
                                                       pos_map, out);
}